// Round 1
// baseline (2166.093 us; speedup 1.0000x reference)
//
#include <hip/hip_runtime.h>
#include <hip/hip_bf16.h>

// ---------------------------------------------------------------------------
// DCLS SimpleCNN forward, fp32 baseline.
// Pipeline: build K1/K2 (bilinear scatter) -> fused conv1+pool+conv2+pool
// (block per image, h1 kept in LDS) -> FC1 (tiled) -> FC2.
// ---------------------------------------------------------------------------

// Build dense (Co,Ci,5,5) kernel from DCLS weights/positions via atomic scatter.
__global__ void build_dcls(const float* __restrict__ w, const float* __restrict__ p,
                           float* __restrict__ K, int total, int Kc) {
    for (int idx = blockIdx.x * blockDim.x + threadIdx.x; idx < total;
         idx += gridDim.x * blockDim.x) {
        float wv = w[idx];
        float pa = p[idx];          // p[0,...]
        float pb = p[total + idx];  // p[1,...]
        float pos1 = fminf(fmaxf(pa, -2.f), 2.f) + 2.f;  // [0,4]
        float pos2 = fminf(fmaxf(pb, -2.f), 2.f) + 2.f;
        int i1 = (int)floorf(pos1);
        int i2 = (int)floorf(pos2);
        float r1 = pos1 - (float)i1;
        float r2 = pos2 - (float)i2;
        int cell = idx / Kc;  // co*Ci + ci
        float* Kb = K + cell * 25;
        float w00 = wv * (1.f - r1) * (1.f - r2);
        float w10 = wv * r1 * (1.f - r2);
        float w01 = wv * (1.f - r1) * r2;
        float w11 = wv * r1 * r2;
        atomicAdd(&Kb[i1 * 5 + i2], w00);
        if (i1 + 1 < 5) atomicAdd(&Kb[(i1 + 1) * 5 + i2], w10);
        if (i2 + 1 < 5) atomicAdd(&Kb[i1 * 5 + i2 + 1], w01);
        if (i1 + 1 < 5 && i2 + 1 < 5) atomicAdd(&Kb[(i1 + 1) * 5 + i2 + 1], w11);
    }
}

// fc1_w (128,3136) -> wT (3136,128), write-coalesced.
__global__ void transpose_fc1(const float* __restrict__ w, float* __restrict__ wT) {
    int idx = blockIdx.x * blockDim.x + threadIdx.x;
    if (idx < 128 * 3136) {
        int k = idx >> 7;        // 0..3135
        int n = idx & 127;       // 0..127
        wT[idx] = w[n * 3136 + k];
    }
}

// ---------------------------------------------------------------------------
// Fused: conv1(1->32, 5x5, pad2) + bias + relu + maxpool2  (h1 in LDS)
//        conv2(32->64, 5x5, pad2) + bias + relu + maxpool2 -> h2 global
// One block (256 threads) per image. Register-blocked 4x4 conv tiles
// (= 2x2 pooled outputs per thread) keep ds:fma ratio ~0.16 (VALU-bound).
// ---------------------------------------------------------------------------
__global__ __launch_bounds__(256, 2) void fused_conv(
    const float* __restrict__ x,    // (B,1,28,28)
    const float* __restrict__ K1,   // (32,1,5,5)
    const float* __restrict__ K2,   // (64,32,5,5)
    const float* __restrict__ b1,   // (32,)
    const float* __restrict__ b2,   // (64,)
    float* __restrict__ h2) {       // (B,64,7,7)
    __shared__ float sm_x[784];       // 28*28
    __shared__ float sm_h1[32 * 196]; // 32 x 14 x 14
    __shared__ float sm_k1[800];      // 32 x 25

    const int b = blockIdx.x;
    const int tid = threadIdx.x;

    // stage input image + K1
    const float* xb = x + (size_t)b * 784;
    for (int t = tid; t < 784; t += 256) sm_x[t] = xb[t];
    for (int t = tid; t < 800; t += 256) sm_k1[t] = K1[t];
    __syncthreads();

    // ---- conv1: jobs = 32co * 49 quads (quad = 2x2 pooled = 4x4 conv px) ----
    for (int j = tid; j < 32 * 49; j += 256) {
        int co = j / 49;
        int q = j - co * 49;
        int qy = q / 7;
        int qx = q - qy * 7;
        int y0 = 4 * qy - 2, x0 = 4 * qx - 2;

        float kv[25];
#pragma unroll
        for (int i = 0; i < 25; ++i) kv[i] = sm_k1[co * 25 + i];

        float patch[8][8];
#pragma unroll
        for (int r = 0; r < 8; ++r) {
            int iy = y0 + r;
            bool rok = (unsigned)iy < 28u;
            int cy = min(max(iy, 0), 27);
#pragma unroll
            for (int c = 0; c < 8; ++c) {
                int ix = x0 + c;
                bool ok = rok && ((unsigned)ix < 28u);
                int cx = min(max(ix, 0), 27);
                float v = sm_x[cy * 28 + cx];
                patch[r][c] = ok ? v : 0.f;
            }
        }
        float acc[4][4];
#pragma unroll
        for (int dy = 0; dy < 4; ++dy)
#pragma unroll
            for (int dx = 0; dx < 4; ++dx) acc[dy][dx] = 0.f;
#pragma unroll
        for (int ky = 0; ky < 5; ++ky)
#pragma unroll
            for (int kx = 0; kx < 5; ++kx) {
                float w = kv[ky * 5 + kx];
#pragma unroll
                for (int dy = 0; dy < 4; ++dy)
#pragma unroll
                    for (int dx = 0; dx < 4; ++dx)
                        acc[dy][dx] += patch[ky + dy][kx + dx] * w;
            }
        float bias = b1[co];
#pragma unroll
        for (int py = 0; py < 2; ++py)
#pragma unroll
            for (int px = 0; px < 2; ++px) {
                float m = fmaxf(fmaxf(acc[2 * py][2 * px], acc[2 * py][2 * px + 1]),
                                fmaxf(acc[2 * py + 1][2 * px], acc[2 * py + 1][2 * px + 1]));
                sm_h1[co * 196 + (2 * qy + py) * 14 + (2 * qx + px)] =
                    fmaxf(m + bias, 0.f);
            }
    }
    __syncthreads();

    // ---- conv2: jobs = 64co * 16 quads (4x4 quad grid covers pooled 8x8, mask to 7x7)
    // weights streamed from global (L1/L2-resident, broadcast across lanes)
    for (int j = tid; j < 64 * 16; j += 256) {
        int co = j >> 4;
        int q = j & 15;
        int qy = q >> 2;
        int qx = q & 3;
        int y0 = 4 * qy - 2, x0 = 4 * qx - 2;

        float acc[4][4];
#pragma unroll
        for (int dy = 0; dy < 4; ++dy)
#pragma unroll
            for (int dx = 0; dx < 4; ++dx) acc[dy][dx] = 0.f;

        const float* kbase = K2 + (size_t)co * 800;
        for (int ci = 0; ci < 32; ++ci) {
            const float* img = sm_h1 + ci * 196;
            float patch[8][8];
#pragma unroll
            for (int r = 0; r < 8; ++r) {
                int iy = y0 + r;
                bool rok = (unsigned)iy < 14u;
                int cy = min(max(iy, 0), 13);
#pragma unroll
                for (int c = 0; c < 8; ++c) {
                    int ix = x0 + c;
                    bool ok = rok && ((unsigned)ix < 14u);
                    int cx = min(max(ix, 0), 13);
                    float v = img[cy * 14 + cx];
                    patch[r][c] = ok ? v : 0.f;
                }
            }
            const float* kp = kbase + ci * 25;
            float kv[25];
#pragma unroll
            for (int i = 0; i < 25; ++i) kv[i] = kp[i];
#pragma unroll
            for (int ky = 0; ky < 5; ++ky)
#pragma unroll
                for (int kx = 0; kx < 5; ++kx) {
                    float w = kv[ky * 5 + kx];
#pragma unroll
                    for (int dy = 0; dy < 4; ++dy)
#pragma unroll
                        for (int dx = 0; dx < 4; ++dx)
                            acc[dy][dx] += patch[ky + dy][kx + dx] * w;
                }
        }
        float bias = b2[co];
        float* outb = h2 + ((size_t)b * 64 + co) * 49;
#pragma unroll
        for (int py = 0; py < 2; ++py)
#pragma unroll
            for (int px = 0; px < 2; ++px) {
                int pr = 2 * qy + py, pc = 2 * qx + px;
                if (pr < 7 && pc < 7) {
                    float m = fmaxf(fmaxf(acc[2 * py][2 * px], acc[2 * py][2 * px + 1]),
                                    fmaxf(acc[2 * py + 1][2 * px], acc[2 * py + 1][2 * px + 1]));
                    outb[pr * 7 + pc] = fmaxf(m + bias, 0.f);
                }
            }
    }
}

// ---------------------------------------------------------------------------
// FC1: out(4096,128) = relu(A(4096,3136) @ WT(3136,128) + b)
// BM=32 rows/block, KT=64, 256 threads = 128 cols x 2 row-groups, 16 acc/thread.
// ---------------------------------------------------------------------------
__global__ __launch_bounds__(256) void fc1_kernel(
    const float* __restrict__ A, const float* __restrict__ WT,
    const float* __restrict__ bias, float* __restrict__ out) {
    __shared__ float smA[64 * 68];   // [k][row], stride 68 (16B-aligned rows)
    __shared__ float smW[64 * 128];  // [k][n]
    const int t = threadIdx.x;
    const int n = t & 127;
    const int rg = t >> 7;  // 0..1 -> rows rg*16 .. rg*16+15
    const int b0 = blockIdx.x * 32;

    float acc[16];
#pragma unroll
    for (int i = 0; i < 16; ++i) acc[i] = 0.f;

    for (int k0 = 0; k0 < 3136; k0 += 64) {
        __syncthreads();
#pragma unroll
        for (int i = 0; i < 2; ++i) {
            int idx = t + i * 256;            // 0..511 float4 loads
            int r = idx >> 4;                 // 0..31
            int kk = (idx & 15) << 2;         // 0,4,...,60
            float4 v = *(const float4*)(A + (size_t)(b0 + r) * 3136 + k0 + kk);
            smA[(kk + 0) * 68 + r] = v.x;
            smA[(kk + 1) * 68 + r] = v.y;
            smA[(kk + 2) * 68 + r] = v.z;
            smA[(kk + 3) * 68 + r] = v.w;
        }
#pragma unroll
        for (int i = 0; i < 8; ++i) {
            int idx = t + i * 256;
            ((float4*)smW)[idx] = ((const float4*)(WT + (size_t)k0 * 128))[idx];
        }
        __syncthreads();
#pragma unroll 8
        for (int k = 0; k < 64; ++k) {
            float w = smW[k * 128 + n];
            const float* ap = &smA[k * 68 + rg * 16];
#pragma unroll
            for (int jj = 0; jj < 4; ++jj) {
                float4 a = *(const float4*)(ap + 4 * jj);
                acc[4 * jj + 0] += a.x * w;
                acc[4 * jj + 1] += a.y * w;
                acc[4 * jj + 2] += a.z * w;
                acc[4 * jj + 3] += a.w * w;
            }
        }
    }
    float bs = bias[n];
#pragma unroll
    for (int jj = 0; jj < 16; ++jj) {
        int row = b0 + rg * 16 + jj;
        out[(size_t)row * 128 + n] = fmaxf(acc[jj] + bs, 0.f);
    }
}

// FC2: out(4096,10) = A(4096,128) @ W(10,128)^T + b
__global__ __launch_bounds__(256) void fc2_kernel(
    const float* __restrict__ A, const float* __restrict__ W,
    const float* __restrict__ bias, float* __restrict__ out, int total) {
    __shared__ float smW[1280];
    __shared__ float smB[10];
    int t = threadIdx.x;
    for (int i = t; i < 1280; i += 256) smW[i] = W[i];
    if (t < 10) smB[t] = bias[t];
    __syncthreads();
    int idx = blockIdx.x * 256 + t;
    if (idx < total) {
        int b = idx / 10;
        int n = idx - b * 10;
        const float* row = A + (size_t)b * 128;
        const float* wr = smW + n * 128;
        float acc = smB[n];
#pragma unroll 8
        for (int k = 0; k < 128; ++k) acc += row[k] * wr[k];
        out[idx] = acc;
    }
}

extern "C" void kernel_launch(void* const* d_in, const int* in_sizes, int n_in,
                              void* d_out, int out_size, void* d_ws, size_t ws_size,
                              hipStream_t stream) {
    const float* x    = (const float*)d_in[0];
    const float* w1   = (const float*)d_in[1];
    const float* p1   = (const float*)d_in[2];
    const float* b1   = (const float*)d_in[3];
    const float* w2   = (const float*)d_in[4];
    const float* p2   = (const float*)d_in[5];
    const float* b2   = (const float*)d_in[6];
    const float* fc1w = (const float*)d_in[7];
    const float* fc1b = (const float*)d_in[8];
    const float* fc2w = (const float*)d_in[9];
    const float* fc2b = (const float*)d_in[10];
    float* out = (float*)d_out;

    const int B = in_sizes[0] / 784;  // 4096

    float* ws = (float*)d_ws;
    float* K1f  = ws;                         // 800
    float* K2f  = ws + 800;                   // 51200
    float* h2   = ws + 52000;                 // B*3136
    float* fc1o = h2 + (size_t)B * 3136;      // B*128
    float* wT   = fc1o + (size_t)B * 128;     // 401408

    // zero the scatter targets (ws is poisoned each call)
    hipMemsetAsync(ws, 0, 52000 * sizeof(float), stream);

    build_dcls<<<2, 256, 0, stream>>>(w1, p1, K1f, 32 * 1 * 16, 16);
    build_dcls<<<256, 256, 0, stream>>>(w2, p2, K2f, 64 * 32 * 32, 32);
    transpose_fc1<<<(128 * 3136 + 255) / 256, 256, 0, stream>>>(fc1w, wT);

    fused_conv<<<B, 256, 0, stream>>>(x, K1f, K2f, b1, b2, h2);
    fc1_kernel<<<B / 32, 256, 0, stream>>>(h2, wT, fc1b, fc1o);
    fc2_kernel<<<(B * 10 + 255) / 256, 256, 0, stream>>>(fc1o, fc2w, fc2b, out, B * 10);
}

// Round 2
// 772.389 us; speedup vs baseline: 2.8044x; 2.8044x over previous
//
#include <hip/hip_runtime.h>
#include <hip/hip_bf16.h>

typedef __attribute__((ext_vector_type(8))) short short8;
typedef __attribute__((ext_vector_type(4))) float float4v;

static __device__ __forceinline__ unsigned short f2bf(float f) {
    unsigned u = __float_as_uint(f);
    unsigned r = (u + 0x7FFF + ((u >> 16) & 1)) >> 16;  // RNE
    return (unsigned short)r;
}

// ---------------------------------------------------------------------------
// Build dense (Co,Ci,5,5) kernel from DCLS weights/positions via atomic scatter.
__global__ void build_dcls(const float* __restrict__ w, const float* __restrict__ p,
                           float* __restrict__ K, int total, int Kc) {
    for (int idx = blockIdx.x * blockDim.x + threadIdx.x; idx < total;
         idx += gridDim.x * blockDim.x) {
        float wv = w[idx];
        float pa = p[idx];
        float pb = p[total + idx];
        float pos1 = fminf(fmaxf(pa, -2.f), 2.f) + 2.f;
        float pos2 = fminf(fmaxf(pb, -2.f), 2.f) + 2.f;
        int i1 = (int)floorf(pos1);
        int i2 = (int)floorf(pos2);
        float r1 = pos1 - (float)i1;
        float r2 = pos2 - (float)i2;
        int cell = idx / Kc;
        float* Kb = K + cell * 25;
        atomicAdd(&Kb[i1 * 5 + i2], wv * (1.f - r1) * (1.f - r2));
        if (i1 + 1 < 5) atomicAdd(&Kb[(i1 + 1) * 5 + i2], wv * r1 * (1.f - r2));
        if (i2 + 1 < 5) atomicAdd(&Kb[i1 * 5 + i2 + 1], wv * (1.f - r1) * r2);
        if (i1 + 1 < 5 && i2 + 1 < 5) atomicAdd(&Kb[(i1 + 1) * 5 + i2 + 1], wv * r1 * r2);
    }
}

// K2f (64,32,5,5) fp32 -> Kt[kk][co][ci] bf16  (A-fragment friendly layout)
__global__ void prep_kt(const float* __restrict__ K2f, unsigned short* __restrict__ Kt) {
    int idx = blockIdx.x * blockDim.x + threadIdx.x;
    if (idx < 25 * 64 * 32) {
        int kk = idx >> 11;          // /2048
        int co = (idx >> 5) & 63;
        int ci = idx & 31;
        Kt[idx] = f2bf(K2f[(co * 32 + ci) * 25 + kk]);
    }
}

// fc1_w (128,3136) -> wT (3136,128)
__global__ void transpose_fc1(const float* __restrict__ w, float* __restrict__ wT) {
    int idx = blockIdx.x * blockDim.x + threadIdx.x;
    if (idx < 128 * 3136) {
        int k = idx >> 7;
        int n = idx & 127;
        wT[idx] = w[n * 3136 + k];
    }
}

// ---------------------------------------------------------------------------
// Fused: conv1(fp32 VALU) + pool -> h1p (LDS, bf16, channel-last, zero-padded)
//        conv2 via 25x shift-GEMM MFMA 16x16x32 bf16, in-register shfl maxpool
// One block (256 thr = 4 waves) per image. Wave w owns co-tile w (16 cos).
// h1p cell stride 40 bf16 (80 B = 20 banks -> conflict-free b128 reads).
// ---------------------------------------------------------------------------
__global__ __launch_bounds__(256, 3) void fused_conv_mfma(
    const float* __restrict__ x,            // (B,1,28,28)
    const float* __restrict__ K1,           // (32,25) fp32
    const unsigned short* __restrict__ Kt,  // (25,64,32) bf16
    const float* __restrict__ b1,
    const float* __restrict__ b2,
    float* __restrict__ h2) {               // (B,64,7,7)
    __shared__ float sm_x[784];
    __shared__ float sm_k1[800];
    __shared__ unsigned short h1p[18 * 20 * 40];  // 28800 B, [yy][xx][ci(+pad)]

    const int b = blockIdx.x;
    const int tid = threadIdx.x;

    // zero h1p (border + pads must be 0), stage x and K1
    for (int t = tid; t < 7200; t += 256) ((unsigned int*)h1p)[t] = 0u;
    const float* xb = x + (size_t)b * 784;
    for (int t = tid; t < 784; t += 256) sm_x[t] = xb[t];
    for (int t = tid; t < 800; t += 256) sm_k1[t] = K1[t];
    __syncthreads();

    // ---- conv1: 32co * 49 quads (quad = 2x2 pooled = 4x4 conv px), fp32 ----
    for (int j = tid; j < 32 * 49; j += 256) {
        int co = j / 49;
        int q = j - co * 49;
        int qy = q / 7;
        int qx = q - qy * 7;
        int y0 = 4 * qy - 2, x0 = 4 * qx - 2;

        float kv[25];
#pragma unroll
        for (int i = 0; i < 25; ++i) kv[i] = sm_k1[co * 25 + i];

        float patch[8][8];
#pragma unroll
        for (int r = 0; r < 8; ++r) {
            int iy = y0 + r;
            bool rok = (unsigned)iy < 28u;
            int cy = min(max(iy, 0), 27);
#pragma unroll
            for (int c = 0; c < 8; ++c) {
                int ix = x0 + c;
                bool ok = rok && ((unsigned)ix < 28u);
                int cx = min(max(ix, 0), 27);
                float v = sm_x[cy * 28 + cx];
                patch[r][c] = ok ? v : 0.f;
            }
        }
        float acc[4][4];
#pragma unroll
        for (int dy = 0; dy < 4; ++dy)
#pragma unroll
            for (int dx = 0; dx < 4; ++dx) acc[dy][dx] = 0.f;
#pragma unroll
        for (int ky = 0; ky < 5; ++ky)
#pragma unroll
            for (int kx = 0; kx < 5; ++kx) {
                float w = kv[ky * 5 + kx];
#pragma unroll
                for (int dy = 0; dy < 4; ++dy)
#pragma unroll
                    for (int dx = 0; dx < 4; ++dx)
                        acc[dy][dx] += patch[ky + dy][kx + dx] * w;
            }
        float bias = b1[co];
#pragma unroll
        for (int py = 0; py < 2; ++py)
#pragma unroll
            for (int px = 0; px < 2; ++px) {
                float m = fmaxf(fmaxf(acc[2 * py][2 * px], acc[2 * py][2 * px + 1]),
                                fmaxf(acc[2 * py + 1][2 * px], acc[2 * py + 1][2 * px + 1]));
                int y1 = 2 * qy + py, x1 = 2 * qx + px;  // 0..13
                h1p[((y1 + 2) * 20 + (x1 + 2)) * 40 + co] = f2bf(fmaxf(m + bias, 0.f));
            }
    }

    // ---- A-fragments: Kt[kk][co][ci], 25 x short8 in registers (global, L2-hot)
    const int lane = tid & 63;
    const int wv = tid >> 6;      // wave id = co-tile
    const int n16 = lane & 15;    // A: m (co). B: n (spatial). D: col n.
    const int cig = lane >> 4;    // k-group: ci = cig*8 + j
    short8 afr[25];
#pragma unroll
    for (int kk = 0; kk < 25; ++kk)
        afr[kk] = *(const short8*)(Kt + ((kk * 64 + wv * 16 + n16) * 32 + cig * 8));

    float bias_r[4];
#pragma unroll
    for (int r = 0; r < 4; ++r) bias_r[r] = b2[wv * 16 + 4 * cig + r];

    __syncthreads();

    // ---- conv2 + in-register maxpool: 14 n-tiles (7 y-pairs x 2 x-halves) ----
    float* outb = h2 + (size_t)b * 3136;
    for (int nt = 0; nt < 14; ++nt) {
        int ty = nt >> 1;   // 0..6 (rows 2ty, 2ty+1)
        int xh = nt & 1;    // x half: cols 8xh .. 8xh+7
        int y = 2 * ty + (n16 >> 3);   // 0..13
        int xcol = 8 * xh + (n16 & 7); // 0..15 (14,15 phantom -> zeros)
        const unsigned short* bbase = h1p + (y * 20 + xcol) * 40 + cig * 8;

        float4v acc = {0.f, 0.f, 0.f, 0.f};
#pragma unroll
        for (int ky = 0; ky < 5; ++ky)
#pragma unroll
            for (int kx = 0; kx < 5; ++kx) {
                short8 bf = *(const short8*)(bbase + (ky * 20 + kx) * 40);
                acc = __builtin_amdgcn_mfma_f32_16x16x32_bf16(afr[ky * 5 + kx], bf, acc, 0, 0, 0);
            }
        // D row m = 4*cig + r (co), col n = spatial. Pool 2x2 via shfl (x-pair ^1, y-pair ^8)
#pragma unroll
        for (int r = 0; r < 4; ++r) {
            float v = acc[r];
            v = fmaxf(v, __shfl_xor(v, 1));
            v = fmaxf(v, __shfl_xor(v, 8));
            if ((n16 & 9) == 0) {  // n16 in {0,2,4,6}
                int xo = 4 * xh + (n16 >> 1);
                if (xo < 7) {
                    int co = wv * 16 + 4 * cig + r;
                    outb[co * 49 + ty * 7 + xo] = fmaxf(v + bias_r[r], 0.f);
                }
            }
        }
    }
}

// ---------------------------------------------------------------------------
// FC1: out(B,128) = relu(A(B,3136) @ WT(3136,128) + b)
__global__ __launch_bounds__(256) void fc1_kernel(
    const float* __restrict__ A, const float* __restrict__ WT,
    const float* __restrict__ bias, float* __restrict__ out) {
    __shared__ float smA[64 * 68];
    __shared__ float smW[64 * 128];
    const int t = threadIdx.x;
    const int n = t & 127;
    const int rg = t >> 7;
    const int b0 = blockIdx.x * 32;

    float acc[16];
#pragma unroll
    for (int i = 0; i < 16; ++i) acc[i] = 0.f;

    for (int k0 = 0; k0 < 3136; k0 += 64) {
        __syncthreads();
#pragma unroll
        for (int i = 0; i < 2; ++i) {
            int idx = t + i * 256;
            int r = idx >> 4;
            int kk = (idx & 15) << 2;
            float4 v = *(const float4*)(A + (size_t)(b0 + r) * 3136 + k0 + kk);
            smA[(kk + 0) * 68 + r] = v.x;
            smA[(kk + 1) * 68 + r] = v.y;
            smA[(kk + 2) * 68 + r] = v.z;
            smA[(kk + 3) * 68 + r] = v.w;
        }
#pragma unroll
        for (int i = 0; i < 8; ++i) {
            int idx = t + i * 256;
            ((float4*)smW)[idx] = ((const float4*)(WT + (size_t)k0 * 128))[idx];
        }
        __syncthreads();
#pragma unroll 8
        for (int k = 0; k < 64; ++k) {
            float w = smW[k * 128 + n];
            const float* ap = &smA[k * 68 + rg * 16];
#pragma unroll
            for (int jj = 0; jj < 4; ++jj) {
                float4 a = *(const float4*)(ap + 4 * jj);
                acc[4 * jj + 0] += a.x * w;
                acc[4 * jj + 1] += a.y * w;
                acc[4 * jj + 2] += a.z * w;
                acc[4 * jj + 3] += a.w * w;
            }
        }
    }
    float bs = bias[n];
#pragma unroll
    for (int jj = 0; jj < 16; ++jj) {
        int row = b0 + rg * 16 + jj;
        out[(size_t)row * 128 + n] = fmaxf(acc[jj] + bs, 0.f);
    }
}

// FC2: out(B,10) = A(B,128) @ W(10,128)^T + b
__global__ __launch_bounds__(256) void fc2_kernel(
    const float* __restrict__ A, const float* __restrict__ W,
    const float* __restrict__ bias, float* __restrict__ out, int total) {
    __shared__ float smW[1280];
    __shared__ float smB[10];
    int t = threadIdx.x;
    for (int i = t; i < 1280; i += 256) smW[i] = W[i];
    if (t < 10) smB[t] = bias[t];
    __syncthreads();
    int idx = blockIdx.x * 256 + t;
    if (idx < total) {
        int b = idx / 10;
        int n = idx - b * 10;
        const float* row = A + (size_t)b * 128;
        const float* wr = smW + n * 128;
        float acc = smB[n];
#pragma unroll 8
        for (int k = 0; k < 128; ++k) acc += row[k] * wr[k];
        out[idx] = acc;
    }
}

extern "C" void kernel_launch(void* const* d_in, const int* in_sizes, int n_in,
                              void* d_out, int out_size, void* d_ws, size_t ws_size,
                              hipStream_t stream) {
    const float* x    = (const float*)d_in[0];
    const float* w1   = (const float*)d_in[1];
    const float* p1   = (const float*)d_in[2];
    const float* b1   = (const float*)d_in[3];
    const float* w2   = (const float*)d_in[4];
    const float* p2   = (const float*)d_in[5];
    const float* b2   = (const float*)d_in[6];
    const float* fc1w = (const float*)d_in[7];
    const float* fc1b = (const float*)d_in[8];
    const float* fc2w = (const float*)d_in[9];
    const float* fc2b = (const float*)d_in[10];
    float* out = (float*)d_out;

    const int B = in_sizes[0] / 784;

    float* ws = (float*)d_ws;
    float* K1f = ws;                               // 800 f
    float* K2f = ws + 800;                         // 51200 f
    unsigned short* Kt = (unsigned short*)(ws + 52000);  // 51200 bf16 = 25600 f
    float* h2   = ws + 52000 + 25600;              // B*3136 f
    float* fc1o = h2 + (size_t)B * 3136;           // B*128 f
    float* wT   = fc1o + (size_t)B * 128;          // 401408 f

    hipMemsetAsync(ws, 0, 52000 * sizeof(float), stream);

    build_dcls<<<2, 256, 0, stream>>>(w1, p1, K1f, 32 * 1 * 16, 16);
    build_dcls<<<256, 256, 0, stream>>>(w2, p2, K2f, 64 * 32 * 32, 32);
    prep_kt<<<(25 * 64 * 32 + 255) / 256, 256, 0, stream>>>(K2f, Kt);
    transpose_fc1<<<(128 * 3136 + 255) / 256, 256, 0, stream>>>(fc1w, wT);

    fused_conv_mfma<<<B, 256, 0, stream>>>(x, K1f, Kt, b1, b2, h2);
    fc1_kernel<<<B / 32, 256, 0, stream>>>(h2, wT, fc1b, fc1o);
    fc2_kernel<<<(B * 10 + 255) / 256, 256, 0, stream>>>(fc1o, fc2w, fc2b, out, B * 10);
}

// Round 3
// 308.493 us; speedup vs baseline: 7.0215x; 2.5037x over previous
//
#include <hip/hip_runtime.h>
#include <hip/hip_bf16.h>

typedef __attribute__((ext_vector_type(8))) short short8;
typedef __attribute__((ext_vector_type(4))) float float4v;

static __device__ __forceinline__ unsigned short f2bf(float f) {
    unsigned u = __float_as_uint(f);
    unsigned r = (u + 0x7FFF + ((u >> 16) & 1)) >> 16;  // RNE
    return (unsigned short)r;
}

// ---------------------------------------------------------------------------
// Build dense (Co,Ci,5,5) kernel from DCLS weights/positions via atomic scatter.
__global__ void build_dcls(const float* __restrict__ w, const float* __restrict__ p,
                           float* __restrict__ K, int total, int Kc) {
    for (int idx = blockIdx.x * blockDim.x + threadIdx.x; idx < total;
         idx += gridDim.x * blockDim.x) {
        float wv = w[idx];
        float pa = p[idx];
        float pb = p[total + idx];
        float pos1 = fminf(fmaxf(pa, -2.f), 2.f) + 2.f;
        float pos2 = fminf(fmaxf(pb, -2.f), 2.f) + 2.f;
        int i1 = (int)floorf(pos1);
        int i2 = (int)floorf(pos2);
        float r1 = pos1 - (float)i1;
        float r2 = pos2 - (float)i2;
        int cell = idx / Kc;
        float* Kb = K + cell * 25;
        atomicAdd(&Kb[i1 * 5 + i2], wv * (1.f - r1) * (1.f - r2));
        if (i1 + 1 < 5) atomicAdd(&Kb[(i1 + 1) * 5 + i2], wv * r1 * (1.f - r2));
        if (i2 + 1 < 5) atomicAdd(&Kb[i1 * 5 + i2 + 1], wv * (1.f - r1) * r2);
        if (i1 + 1 < 5 && i2 + 1 < 5) atomicAdd(&Kb[(i1 + 1) * 5 + i2 + 1], wv * r1 * r2);
    }
}

// K2f (64,32,5,5) fp32 -> Kt[kk][co][ci] bf16  (A-fragment friendly layout)
__global__ void prep_kt(const float* __restrict__ K2f, unsigned short* __restrict__ Kt) {
    int idx = blockIdx.x * blockDim.x + threadIdx.x;
    if (idx < 25 * 64 * 32) {
        int kk = idx >> 11;
        int co = (idx >> 5) & 63;
        int ci = idx & 31;
        Kt[idx] = f2bf(K2f[(co * 32 + ci) * 25 + kk]);
    }
}

// fc1_w (128,3136) fp32 -> bf16, same layout (= MFMA B-fragment friendly)
__global__ void prep_w1b(const float* __restrict__ w, unsigned short* __restrict__ wb,
                         int total) {
    int idx = blockIdx.x * blockDim.x + threadIdx.x;
    if (idx < total) wb[idx] = f2bf(w[idx]);
}

// ---------------------------------------------------------------------------
// Fused: conv1 (fp32 VALU, zero-padded LDS image, b128 patch loads) + pool ->
//        h1p (LDS bf16 channel-last zero-padded) ->
//        conv2 via shift-GEMM MFMA (waves own nt-groups; A-frags from global)
//        + in-register shfl maxpool -> h2 bf16.
// One block (4 waves) per image.
// ---------------------------------------------------------------------------
__global__ __launch_bounds__(256, 3) void fused_conv_mfma(
    const float* __restrict__ x,            // (B,1,28,28)
    const float* __restrict__ K1,           // (32,25) fp32
    const unsigned short* __restrict__ Kt,  // (25,64,32) bf16
    const float* __restrict__ b1,
    const float* __restrict__ b2,
    unsigned short* __restrict__ h2) {      // (B,64,7,7) bf16
    __shared__ __align__(16) float sm_xp[32 * 36];            // padded image, stride 36
    __shared__ __align__(16) float sm_k1[800];
    __shared__ __align__(16) unsigned short h1p[18 * 20 * 40]; // [yy][xx][ci(+pad)]

    const int b = blockIdx.x;
    const int tid = threadIdx.x;

    // zero padded buffers
    for (int t = tid; t < 288; t += 256) ((uint4*)sm_xp)[t] = uint4{0, 0, 0, 0};
    for (int t = tid; t < 1800; t += 256) ((uint4*)h1p)[t] = uint4{0, 0, 0, 0};
    __syncthreads();

    // stage x interior + K1
    const float* xb = x + (size_t)b * 784;
    for (int t = tid; t < 784; t += 256) {
        int row = t / 28, col = t - row * 28;
        sm_xp[(row + 2) * 36 + col + 2] = xb[t];
    }
    for (int t = tid; t < 800; t += 256) sm_k1[t] = K1[t];
    __syncthreads();

    // ---- conv1: 32co * 49 quads, fp32, no bounds checks (padded) ----
    for (int j = tid; j < 32 * 49; j += 256) {
        int co = j / 49;
        int q = j - co * 49;
        int qy = q / 7;
        int qx = q - qy * 7;

        float kv[25];
#pragma unroll
        for (int i = 0; i < 25; ++i) kv[i] = sm_k1[co * 25 + i];

        float patch[8][8];
#pragma unroll
        for (int r = 0; r < 8; ++r) {
            float4 p0 = *(const float4*)&sm_xp[(4 * qy + r) * 36 + 4 * qx];
            float4 p1 = *(const float4*)&sm_xp[(4 * qy + r) * 36 + 4 * qx + 4];
            patch[r][0] = p0.x; patch[r][1] = p0.y; patch[r][2] = p0.z; patch[r][3] = p0.w;
            patch[r][4] = p1.x; patch[r][5] = p1.y; patch[r][6] = p1.z; patch[r][7] = p1.w;
        }
        float acc[4][4];
#pragma unroll
        for (int dy = 0; dy < 4; ++dy)
#pragma unroll
            for (int dx = 0; dx < 4; ++dx) acc[dy][dx] = 0.f;
#pragma unroll
        for (int ky = 0; ky < 5; ++ky)
#pragma unroll
            for (int kx = 0; kx < 5; ++kx) {
                float w = kv[ky * 5 + kx];
#pragma unroll
                for (int dy = 0; dy < 4; ++dy)
#pragma unroll
                    for (int dx = 0; dx < 4; ++dx)
                        acc[dy][dx] += patch[ky + dy][kx + dx] * w;
            }
        float bias = b1[co];
#pragma unroll
        for (int py = 0; py < 2; ++py)
#pragma unroll
            for (int px = 0; px < 2; ++px) {
                float m = fmaxf(fmaxf(acc[2 * py][2 * px], acc[2 * py][2 * px + 1]),
                                fmaxf(acc[2 * py + 1][2 * px], acc[2 * py + 1][2 * px + 1]));
                int y1 = 2 * qy + py, x1 = 2 * qx + px;  // 0..13
                h1p[((y1 + 2) * 20 + (x1 + 2)) * 40 + co] = f2bf(fmaxf(m + bias, 0.f));
            }
    }
    __syncthreads();

    // ---- conv2: wave wv handles nt in {wv, wv+4, wv+8, wv+12} (nt<14),
    //      all 64 co per wave (4 co-tiles, A-frags from global Kt). ----
    const int lane = tid & 63;
    const int wv = tid >> 6;
    const int n16 = lane & 15;
    const int cig = lane >> 4;

    int ybase[4], xbase[4], ty_a[4], xh_a[4];
    bool valid[4];
#pragma unroll
    for (int ntl = 0; ntl < 4; ++ntl) {
        int nt = wv + 4 * ntl;
        valid[ntl] = nt < 14;
        int nts = valid[ntl] ? nt : 0;
        int ty = nts >> 1, xh = nts & 1;
        ty_a[ntl] = ty; xh_a[ntl] = xh;
        ybase[ntl] = 2 * ty + (n16 >> 3);
        xbase[ntl] = 8 * xh + (n16 & 7);
    }

    float4v acc[4][4];  // [ntl][cot]
#pragma unroll
    for (int i = 0; i < 4; ++i)
#pragma unroll
        for (int c = 0; c < 4; ++c) acc[i][c] = float4v{0.f, 0.f, 0.f, 0.f};

#pragma unroll
    for (int ky = 0; ky < 5; ++ky) {
#pragma unroll
        for (int kx = 0; kx < 5; ++kx) {
            int kk = ky * 5 + kx;
            short8 afr[4];
#pragma unroll
            for (int cot = 0; cot < 4; ++cot)
                afr[cot] = *(const short8*)(Kt + ((kk * 64 + cot * 16 + n16) * 32 + cig * 8));
#pragma unroll
            for (int ntl = 0; ntl < 4; ++ntl) {
                if (valid[ntl]) {
                    short8 bf = *(const short8*)(h1p +
                        ((ybase[ntl] + ky) * 20 + xbase[ntl] + kx) * 40 + cig * 8);
#pragma unroll
                    for (int cot = 0; cot < 4; ++cot)
                        acc[ntl][cot] = __builtin_amdgcn_mfma_f32_16x16x32_bf16(
                            afr[cot], bf, acc[ntl][cot], 0, 0, 0);
                }
            }
        }
    }

    // epilogue: in-register 2x2 maxpool (shfl xor 1 = x-pair, xor 8 = y-pair)
    unsigned short* outb = h2 + (size_t)b * 3136;
#pragma unroll
    for (int ntl = 0; ntl < 4; ++ntl) {
        if (valid[ntl]) {
#pragma unroll
            for (int cot = 0; cot < 4; ++cot) {
#pragma unroll
                for (int r = 0; r < 4; ++r) {
                    float v = acc[ntl][cot][r];
                    v = fmaxf(v, __shfl_xor(v, 1));
                    v = fmaxf(v, __shfl_xor(v, 8));
                    if ((n16 & 9) == 0) {
                        int xo = 4 * xh_a[ntl] + (n16 >> 1);
                        if (xo < 7) {
                            int co = cot * 16 + 4 * cig + r;
                            float bias = b2[co];
                            outb[co * 49 + ty_a[ntl] * 7 + xo] =
                                f2bf(fmaxf(v + bias, 0.f));
                        }
                    }
                }
            }
        }
    }
}

// ---------------------------------------------------------------------------
// FC1 MFMA: out(B,128) += A(B,3136)bf16 @ W(128,3136)bf16^T  (K-split 2, atomics)
// Block: 16 rows, 4 waves x 32 cols, K-half 1568. No LDS.
__global__ __launch_bounds__(256) void fc1_mfma(
    const unsigned short* __restrict__ A,   // (B,3136) bf16
    const unsigned short* __restrict__ Wb,  // (128,3136) bf16
    float* __restrict__ out) {              // (B,128) f32, pre-zeroed
    const int blk = blockIdx.x;
    const int kh = blk & 1;
    const int m0 = (blk >> 1) * 16;
    const int tid = threadIdx.x;
    const int wv = tid >> 6;
    const int lane = tid & 63;
    const int n16 = lane & 15;
    const int cig = lane >> 4;

    const unsigned short* Arow = A + (size_t)(m0 + n16) * 3136 + cig * 8 + kh * 1568;
    const unsigned short* W0 = Wb + (size_t)(wv * 32 + n16) * 3136 + cig * 8 + kh * 1568;
    const unsigned short* W1 = W0 + 16 * 3136;

    float4v acc0 = {0.f, 0.f, 0.f, 0.f};
    float4v acc1 = {0.f, 0.f, 0.f, 0.f};
#pragma unroll 7
    for (int k = 0; k < 1568; k += 32) {
        short8 a = *(const short8*)(Arow + k);
        short8 w0 = *(const short8*)(W0 + k);
        short8 w1 = *(const short8*)(W1 + k);
        acc0 = __builtin_amdgcn_mfma_f32_16x16x32_bf16(a, w0, acc0, 0, 0, 0);
        acc1 = __builtin_amdgcn_mfma_f32_16x16x32_bf16(a, w1, acc1, 0, 0, 0);
    }
    // D: row m = cig*4+r (batch), col = n16 (out col)
#pragma unroll
    for (int r = 0; r < 4; ++r) {
        int row = m0 + cig * 4 + r;
        atomicAdd(&out[(size_t)row * 128 + wv * 32 + n16], acc0[r]);
        atomicAdd(&out[(size_t)row * 128 + wv * 32 + 16 + n16], acc1[r]);
    }
}

// fc1o: in-place bias + relu (float4)
__global__ void finalize_fc1(float* __restrict__ io, const float* __restrict__ bias,
                             int total4) {
    int idx = blockIdx.x * blockDim.x + threadIdx.x;
    if (idx < total4) {
        float4 v = ((float4*)io)[idx];
        float4 bv = ((const float4*)bias)[idx & 31];
        v.x = fmaxf(v.x + bv.x, 0.f);
        v.y = fmaxf(v.y + bv.y, 0.f);
        v.z = fmaxf(v.z + bv.z, 0.f);
        v.w = fmaxf(v.w + bv.w, 0.f);
        ((float4*)io)[idx] = v;
    }
}

// FC2: out(B,10) = A(B,128) @ W(10,128)^T + b   (A already relu'd)
__global__ __launch_bounds__(256) void fc2_kernel(
    const float* __restrict__ A, const float* __restrict__ W,
    const float* __restrict__ bias, float* __restrict__ out, int total) {
    __shared__ float smW[10 * 132];  // padded stride 132 (kills 10-way bank conflict)
    __shared__ float smB[10];
    int t = threadIdx.x;
    for (int i = t; i < 1280; i += 256) {
        int n = i >> 7, k = i & 127;
        smW[n * 132 + k] = W[i];
    }
    if (t < 10) smB[t] = bias[t];
    __syncthreads();
    int idx = blockIdx.x * 256 + t;
    if (idx < total) {
        int b = idx / 10;
        int n = idx - b * 10;
        const float4* row = (const float4*)(A + (size_t)b * 128);
        const float4* wr = (const float4*)(smW + n * 132);
        float acc = smB[n];
#pragma unroll
        for (int k = 0; k < 32; ++k) {
            float4 a = row[k];
            float4 w = wr[k];
            acc += a.x * w.x + a.y * w.y + a.z * w.z + a.w * w.w;
        }
        out[idx] = acc;
    }
}

extern "C" void kernel_launch(void* const* d_in, const int* in_sizes, int n_in,
                              void* d_out, int out_size, void* d_ws, size_t ws_size,
                              hipStream_t stream) {
    const float* x    = (const float*)d_in[0];
    const float* w1   = (const float*)d_in[1];
    const float* p1   = (const float*)d_in[2];
    const float* b1   = (const float*)d_in[3];
    const float* w2   = (const float*)d_in[4];
    const float* p2   = (const float*)d_in[5];
    const float* b2   = (const float*)d_in[6];
    const float* fc1w = (const float*)d_in[7];
    const float* fc1b = (const float*)d_in[8];
    const float* fc2w = (const float*)d_in[9];
    const float* fc2b = (const float*)d_in[10];
    float* out = (float*)d_out;

    const int B = in_sizes[0] / 784;  // 4096

    float* ws = (float*)d_ws;
    float* K1f = ws;                                      // 800 f
    float* K2f = ws + 800;                                // 51200 f
    unsigned short* Kt  = (unsigned short*)(ws + 52000);  // 51200 bf16
    unsigned short* w1b = (unsigned short*)(ws + 77600);  // 401408 bf16
    unsigned short* h2b = (unsigned short*)(ws + 278304); // B*3136 bf16
    float* fc1o = ws + 278304 + (size_t)B * 1568;         // B*128 f32

    hipMemsetAsync(ws, 0, 52000 * sizeof(float), stream);
    hipMemsetAsync(fc1o, 0, (size_t)B * 128 * sizeof(float), stream);

    build_dcls<<<2, 256, 0, stream>>>(w1, p1, K1f, 32 * 1 * 16, 16);
    build_dcls<<<256, 256, 0, stream>>>(w2, p2, K2f, 64 * 32 * 32, 32);
    prep_kt<<<(25 * 64 * 32 + 255) / 256, 256, 0, stream>>>(K2f, Kt);
    prep_w1b<<<(128 * 3136 + 255) / 256, 256, 0, stream>>>(fc1w, w1b, 128 * 3136);

    fused_conv_mfma<<<B, 256, 0, stream>>>(x, K1f, Kt, b1, b2, h2b);
    fc1_mfma<<<(B / 16) * 2, 256, 0, stream>>>(h2b, w1b, fc1o);
    finalize_fc1<<<(B * 32 + 255) / 256, 256, 0, stream>>>(fc1o, fc1b, B * 32);
    fc2_kernel<<<(B * 10 + 255) / 256, 256, 0, stream>>>(fc1o, fc2w, fc2b, out, B * 10);
}